// Round 4
// baseline (2242.177 us; speedup 1.0000x reference)
//
#include <hip/hip_runtime.h>
#include <hip/hip_bf16.h>

// RecurrentLSTMStack: T=256, B=2048, D=16, H=64, 3 layers.
// R4: 2 independent barrier groups per CU (grid 512 x 512thr, 4 rows/block,
// 4x duplicated N-cols), SROW=208 -> conflict-free LDS reads, layer-diagonal
// pipeline with compile-time parity, shared K-block reads across layers.

#define TT 256
#define BB 2048
#define DD 16
#define HH 64

#define SROW 208                 // halves/row = 104 words; 104%32=8 -> 4 rows x 4 kslots hit all 32 banks
#define NR 4                     // batch rows per block
#define PANEL (NR * SROW)        // 832 halves per parity panel
#define H0O 0
#define H1O 64
#define H2O 128
#define XO  192

typedef __attribute__((ext_vector_type(8))) _Float16 halfx8;
typedef __attribute__((ext_vector_type(8))) unsigned short ushortx8;
typedef __attribute__((ext_vector_type(4))) float floatx4;

#if __has_builtin(__builtin_amdgcn_exp2f)
#define EXP2F(x) __builtin_amdgcn_exp2f(x)
#else
#define EXP2F(x) exp2f(x)
#endif
#if __has_builtin(__builtin_amdgcn_rcpf)
#define RCPF(x) __builtin_amdgcn_rcpf(x)
#else
#define RCPF(x) (1.0f/(x))
#endif

__device__ __forceinline__ float sigm(float x) {
  return RCPF(1.0f + EXP2F(-1.4426950408889634f * x));
}
// no clamp: exp2(+inf)=inf -> rcp=0 -> 1; exp2(-inf)=0 -> 1-2/1 = -1
__device__ __forceinline__ float tanh_f(float x) {
  float t = EXP2F(2.8853900817779268f * x);
  return 1.0f - 2.0f * RCPF(t + 1.0f);
}
// Raw barrier: waits our ds ops, does NOT drain vmcnt (x prefetch stays in flight).
__device__ __forceinline__ void block_sync() {
  asm volatile("s_waitcnt lgkmcnt(0)" ::: "memory");
  __builtin_amdgcn_s_barrier();
}

__global__ void detect_k(const unsigned short* __restrict__ xr, int* __restrict__ flag) {
  int cnt = 0;
  for (int i = threadIdx.x; i < 4096; i += 64) {
    float v = __uint_as_float(((unsigned int)xr[i]) << 16);
    if (!(fabsf(v) < 4.0f)) cnt++;
  }
#pragma unroll
  for (int o = 32; o > 0; o >>= 1) cnt += __shfl_down(cnt, o, 64);
  if (threadIdx.x == 0) flag[0] = (cnt < 100) ? 1 : 0;
}

#define MF(A, B, C) __builtin_amdgcn_mfma_f32_16x16x32_f16(A, B, C, 0, 0, 0)

#define BODY(S_, PPB, PNB)                                                        \
  {                                                                               \
    const int s_ = (S_);                                                          \
    halfx8 xreg = {};                                                             \
    const bool loader = (tid < 2 * NR) && (s_ + 1 < TT);                          \
    if (loader)                                                                   \
      xreg = ld8(xg, ((long)(s_ + 1) * BB + rowbase + (tid >> 1)) * DD + (tid & 1) * 8); \
    block_sync();                                                                 \
    const _Float16* PpR = SH + (PPB) + rd_off;                                    \
    _Float16* Pn = SH + (PNB);                                                    \
    halfx8 r0 = *(const halfx8*)(PpR + 0);                                        \
    halfx8 r1 = *(const halfx8*)(PpR + 32);                                       \
    halfx8 r2 = *(const halfx8*)(PpR + 64);                                       \
    halfx8 r3 = *(const halfx8*)(PpR + 96);                                       \
    halfx8 r4 = *(const halfx8*)(PpR + 128);                                      \
    halfx8 r5 = *(const halfx8*)(PpR + 160);                                      \
    halfx8 r6 = *(const halfx8*)(PpR + 192);                                      \
    floatx4 a00 = bs0[0], a01 = bs0[1];                                           \
    floatx4 a10 = bs1[0], a11 = bs1[1];                                           \
    floatx4 a20 = bs2[0], a21 = bs2[1];                                           \
    a00 = MF(wA0[0][0], r0, a00); a01 = MF(wA0[1][0], r0, a01);                   \
    a10 = MF(wA1[0][0], r0, a10); a11 = MF(wA1[1][0], r0, a11);                   \
    a00 = MF(wA0[0][1], r1, a00); a01 = MF(wA0[1][1], r1, a01);                   \
    a10 = MF(wA1[0][1], r1, a10); a11 = MF(wA1[1][1], r1, a11);                   \
    a20 = MF(wA2[0][0], r2, a20); a21 = MF(wA2[1][0], r2, a21);                   \
    a10 = MF(wA1[0][2], r2, a10); a11 = MF(wA1[1][2], r2, a11);                   \
    a20 = MF(wA2[0][1], r3, a20); a21 = MF(wA2[1][1], r3, a21);                   \
    a10 = MF(wA1[0][3], r3, a10); a11 = MF(wA1[1][3], r3, a11);                   \
    a20 = MF(wA2[0][2], r4, a20); a21 = MF(wA2[1][2], r4, a21);                   \
    a20 = MF(wA2[0][3], r5, a20); a21 = MF(wA2[1][3], r5, a21);                   \
    a00 = MF(wA0[0][2], r6, a00); a01 = MF(wA0[1][2], r6, a01);                   \
    { floatx4 gv = msel ? a01 : a00;                                              \
      float I = sigm(gv[0]), F = sigm(gv[1]), G = tanh_f(gv[2]), O = sigm(gv[3]); \
      float cn = F * c0s + I * G;                                                 \
      float hn = O * tanh_f(cn);                                                  \
      if (s_ < TT) { c0s = cn; if (cmt) Pn[wr_base + H0O] = (_Float16)hn; } }     \
    { floatx4 gv = msel ? a11 : a10;                                              \
      float I = sigm(gv[0]), F = sigm(gv[1]), G = tanh_f(gv[2]), O = sigm(gv[3]); \
      float cn = F * c1s + I * G;                                                 \
      float hn = O * tanh_f(cn);                                                  \
      if (s_ >= 1 && s_ <= TT) { c1s = cn; if (cmt) Pn[wr_base + H1O] = (_Float16)hn; } } \
    { floatx4 gv = msel ? a21 : a20;                                              \
      float I = sigm(gv[0]), F = sigm(gv[1]), G = tanh_f(gv[2]), O = sigm(gv[3]); \
      float cn = F * c2s + I * G;                                                 \
      float hn = O * tanh_f(cn);                                                  \
      if (s_ >= 2) { c2s = cn;                                                    \
        if (cmt) { Pn[wr_base + H2O] = (_Float16)hn;                              \
          long oi = (long)(s_ - 2) * ((long)BB * HH) + olane;                     \
          if (isbf) ((__hip_bfloat16*)outp)[oi] = __float2bfloat16(hn);           \
          else ((float*)outp)[oi] = hn; } } }                                     \
    if (loader) *(halfx8*)&Pn[(tid >> 1) * SROW + XO + (tid & 1) * 8] = xreg;     \
  }

__launch_bounds__(512, 4)
__global__ void lstm3_k(const void* __restrict__ xg,
                        const void* W0i, const void* W0h, const void* B0i, const void* B0h,
                        const void* W1i, const void* W1h, const void* B1i, const void* B1h,
                        const void* W2i, const void* W2h, const void* B2i, const void* B2h,
                        void* __restrict__ outp, const int* __restrict__ flagp) {
  const int tid = threadIdx.x;
  const int w = tid >> 6;        // wave 0..7
  const int lane = tid & 63;
  const int c = lane & 15;       // MFMA col: batch row c&3, 4x duplicated
  const int g = lane >> 4;       // k-slot group
  const int rowbase = blockIdx.x * NR;
  const int isbf = flagp ? flagp[0] : 1;

  // Panel row r (4 rows): [h0(0..63) | h1(64..127) | h2(128..191) | x(192..207)]
  // +32 zeroed tail halves for L0's g>=2 zero-weight over-reads on the last row.
  __shared__ __align__(16) _Float16 SH[2 * PANEL + 32];

  auto ldf = [&](const void* b, long i) -> float {
    return isbf ? __bfloat162float(((const __hip_bfloat16*)b)[i]) : ((const float*)b)[i];
  };
  auto ld8 = [&](const void* b, long i) -> halfx8 {
    halfx8 r;
    if (isbf) {
      ushortx8 raw = *(const ushortx8*)((const unsigned short*)b + i);
#pragma unroll
      for (int j = 0; j < 8; ++j)
        r[j] = (_Float16)__uint_as_float(((unsigned int)raw[j]) << 16);
    } else {
      const float* s = (const float*)b + i;
#pragma unroll
      for (int j = 0; j < 8; ++j) r[j] = (_Float16)s[j];
    }
    return r;
  };

  // ---- persistent weight fragments + combined biases ----
  // Interleaved gate row r_il = 4*unit + q <-> orig row q*64 + unit.
  halfx8 wA0[2][3], wA1[2][4], wA2[2][4];
  floatx4 bs0[2], bs1[2], bs2[2];
#pragma unroll
  for (int m = 0; m < 2; ++m) {
    const int Mt = 2 * w + m;
    const int ril = Mt * 16 + c;
    const int u = ril >> 2, q = ril & 3;
    const long orig = q * 64 + u;
    halfx8 z = {};
    wA0[m][0] = ld8(W0h, orig * 64 + 8 * g);
    wA0[m][1] = ld8(W0h, orig * 64 + 32 + 8 * g);
    wA0[m][2] = (g == 0) ? ld8(W0i, orig * 16)
              : (g == 1) ? ld8(W0i, orig * 16 + 8) : z;
    wA1[m][0] = ld8(W1i, orig * 64 + 8 * g);
    wA1[m][1] = ld8(W1i, orig * 64 + 32 + 8 * g);
    wA1[m][2] = ld8(W1h, orig * 64 + 8 * g);
    wA1[m][3] = ld8(W1h, orig * 64 + 32 + 8 * g);
    wA2[m][0] = ld8(W2i, orig * 64 + 8 * g);
    wA2[m][1] = ld8(W2i, orig * 64 + 32 + 8 * g);
    wA2[m][2] = ld8(W2h, orig * 64 + 8 * g);
    wA2[m][3] = ld8(W2h, orig * 64 + 32 + 8 * g);
    const int ub = 4 * Mt + g;
#pragma unroll
    for (int qq = 0; qq < 4; ++qq) {
      bs0[m][qq] = ldf(B0i, 64 * qq + ub) + ldf(B0h, 64 * qq + ub);
      bs1[m][qq] = ldf(B1i, 64 * qq + ub) + ldf(B1h, 64 * qq + ub);
      bs2[m][qq] = ldf(B2i, 64 * qq + ub) + ldf(B2h, 64 * qq + ub);
    }
  }

  for (int i = tid; i < 2 * PANEL + 32; i += 512) SH[i] = (_Float16)0.0f;
  block_sync();
  if (tid < 2 * NR) {  // stage x[0] into parity-0 panel
    *(halfx8*)&SH[(tid >> 1) * SROW + XO + (tid & 1) * 8] =
        ld8(xg, ((long)0 * BB + rowbase + (tid >> 1)) * DD + (tid & 1) * 8);
  }

  // Cells: lane (c,g) of wave w holds cell (unit 8w+4*msel+g, row c&3), msel=(c>>2)&1.
  // Lanes c>=8 are exact duplicates of c-8; only c<8 commits (cmt).
  const int msel = (c >> 2) & 1;
  const int r_el = c & 3;
  const int u_el = 8 * w + 4 * msel + g;
  const bool cmt = (c < 8);
  const int rd_off = (c & 3) * SROW + 8 * g;
  const int wr_base = r_el * SROW + u_el;
  const long olane = ((long)rowbase + r_el) * HH + u_el;
  float c0s = 0.f, c1s = 0.f, c2s = 0.f;

#pragma unroll 1
  for (int s2 = 0; s2 < (TT + 2) / 2; ++s2) {
    const int s = 2 * s2;
    BODY(s, 0, PANEL)
    BODY(s + 1, PANEL, 0)
  }
}

extern "C" void kernel_launch(void* const* d_in, const int* in_sizes, int n_in,
                              void* d_out, int out_size, void* d_ws, size_t ws_size,
                              hipStream_t stream) {
  (void)in_sizes; (void)n_in; (void)out_size;
  int* flag = (ws_size >= sizeof(int)) ? (int*)d_ws : nullptr;
  if (flag) {
    detect_k<<<dim3(1), dim3(64), 0, stream>>>((const unsigned short*)d_in[0], flag);
  }
  lstm3_k<<<dim3(BB / NR), dim3(512), 0, stream>>>(
      d_in[0],
      d_in[1], d_in[2], d_in[3], d_in[4],
      d_in[5], d_in[6], d_in[7], d_in[8],
      d_in[9], d_in[10], d_in[11], d_in[12],
      d_out, flag);
}

// Round 5
// 517.216 us; speedup vs baseline: 4.3351x; 4.3351x over previous
//
#include <hip/hip_runtime.h>
#include <hip/hip_bf16.h>

// RecurrentLSTMStack: T=256, B=2048, D=16, H=64, 3 layers.
// R5: R4 structure (grid 512 x 512thr, 4 rows/block, 4x duplicated N-cols,
// SROW=208 conflict-free LDS, layer-diagonal pipeline) with launch_bounds
// (512,2): VGPR cap 128 (R3 compiled to 92, no spill) -> 2 blocks/CU
// co-resident = 2 independent barrier groups interleaving their chains.
// R4's (512,4) capped VGPR at 64 -> 4.2GB scratch spill traffic, 8x regression.

#define TT 256
#define BB 2048
#define DD 16
#define HH 64

#define SROW 208                 // halves/row = 104 words; 104%32=8 -> 4 rows x 4 kslots hit all 32 banks
#define NR 4                     // batch rows per block
#define PANEL (NR * SROW)        // 832 halves per parity panel
#define H0O 0
#define H1O 64
#define H2O 128
#define XO  192

typedef __attribute__((ext_vector_type(8))) _Float16 halfx8;
typedef __attribute__((ext_vector_type(8))) unsigned short ushortx8;
typedef __attribute__((ext_vector_type(4))) float floatx4;

#if __has_builtin(__builtin_amdgcn_exp2f)
#define EXP2F(x) __builtin_amdgcn_exp2f(x)
#else
#define EXP2F(x) exp2f(x)
#endif
#if __has_builtin(__builtin_amdgcn_rcpf)
#define RCPF(x) __builtin_amdgcn_rcpf(x)
#else
#define RCPF(x) (1.0f/(x))
#endif

__device__ __forceinline__ float sigm(float x) {
  return RCPF(1.0f + EXP2F(-1.4426950408889634f * x));
}
// no clamp: exp2(+inf)=inf -> rcp=0 -> 1; exp2(-inf)=0 -> 1-2/1 = -1
__device__ __forceinline__ float tanh_f(float x) {
  float t = EXP2F(2.8853900817779268f * x);
  return 1.0f - 2.0f * RCPF(t + 1.0f);
}
// Raw barrier: waits our ds ops, does NOT drain vmcnt (x prefetch stays in flight).
__device__ __forceinline__ void block_sync() {
  asm volatile("s_waitcnt lgkmcnt(0)" ::: "memory");
  __builtin_amdgcn_s_barrier();
}

__global__ void detect_k(const unsigned short* __restrict__ xr, int* __restrict__ flag) {
  int cnt = 0;
  for (int i = threadIdx.x; i < 4096; i += 64) {
    float v = __uint_as_float(((unsigned int)xr[i]) << 16);
    if (!(fabsf(v) < 4.0f)) cnt++;
  }
#pragma unroll
  for (int o = 32; o > 0; o >>= 1) cnt += __shfl_down(cnt, o, 64);
  if (threadIdx.x == 0) flag[0] = (cnt < 100) ? 1 : 0;
}

#define MF(A, B, C) __builtin_amdgcn_mfma_f32_16x16x32_f16(A, B, C, 0, 0, 0)

#define BODY(S_, PPB, PNB)                                                        \
  {                                                                               \
    const int s_ = (S_);                                                          \
    halfx8 xreg = {};                                                             \
    const bool loader = (tid < 2 * NR) && (s_ + 1 < TT);                          \
    if (loader)                                                                   \
      xreg = ld8(xg, ((long)(s_ + 1) * BB + rowbase + (tid >> 1)) * DD + (tid & 1) * 8); \
    block_sync();                                                                 \
    const _Float16* PpR = SH + (PPB) + rd_off;                                    \
    _Float16* Pn = SH + (PNB);                                                    \
    halfx8 r0 = *(const halfx8*)(PpR + 0);                                        \
    halfx8 r1 = *(const halfx8*)(PpR + 32);                                       \
    halfx8 r2 = *(const halfx8*)(PpR + 64);                                       \
    halfx8 r3 = *(const halfx8*)(PpR + 96);                                       \
    halfx8 r4 = *(const halfx8*)(PpR + 128);                                      \
    halfx8 r5 = *(const halfx8*)(PpR + 160);                                      \
    halfx8 r6 = *(const halfx8*)(PpR + 192);                                      \
    floatx4 a00 = bs0[0], a01 = bs0[1];                                           \
    floatx4 a10 = bs1[0], a11 = bs1[1];                                           \
    floatx4 a20 = bs2[0], a21 = bs2[1];                                           \
    a00 = MF(wA0[0][0], r0, a00); a01 = MF(wA0[1][0], r0, a01);                   \
    a10 = MF(wA1[0][0], r0, a10); a11 = MF(wA1[1][0], r0, a11);                   \
    a00 = MF(wA0[0][1], r1, a00); a01 = MF(wA0[1][1], r1, a01);                   \
    a10 = MF(wA1[0][1], r1, a10); a11 = MF(wA1[1][1], r1, a11);                   \
    a20 = MF(wA2[0][0], r2, a20); a21 = MF(wA2[1][0], r2, a21);                   \
    a10 = MF(wA1[0][2], r2, a10); a11 = MF(wA1[1][2], r2, a11);                   \
    a20 = MF(wA2[0][1], r3, a20); a21 = MF(wA2[1][1], r3, a21);                   \
    a10 = MF(wA1[0][3], r3, a10); a11 = MF(wA1[1][3], r3, a11);                   \
    a20 = MF(wA2[0][2], r4, a20); a21 = MF(wA2[1][2], r4, a21);                   \
    a20 = MF(wA2[0][3], r5, a20); a21 = MF(wA2[1][3], r5, a21);                   \
    a00 = MF(wA0[0][2], r6, a00); a01 = MF(wA0[1][2], r6, a01);                   \
    { floatx4 gv = msel ? a01 : a00;                                              \
      float I = sigm(gv[0]), F = sigm(gv[1]), G = tanh_f(gv[2]), O = sigm(gv[3]); \
      float cn = F * c0s + I * G;                                                 \
      float hn = O * tanh_f(cn);                                                  \
      if (s_ < TT) { c0s = cn; if (cmt) Pn[wr_base + H0O] = (_Float16)hn; } }     \
    { floatx4 gv = msel ? a11 : a10;                                              \
      float I = sigm(gv[0]), F = sigm(gv[1]), G = tanh_f(gv[2]), O = sigm(gv[3]); \
      float cn = F * c1s + I * G;                                                 \
      float hn = O * tanh_f(cn);                                                  \
      if (s_ >= 1 && s_ <= TT) { c1s = cn; if (cmt) Pn[wr_base + H1O] = (_Float16)hn; } } \
    { floatx4 gv = msel ? a21 : a20;                                              \
      float I = sigm(gv[0]), F = sigm(gv[1]), G = tanh_f(gv[2]), O = sigm(gv[3]); \
      float cn = F * c2s + I * G;                                                 \
      float hn = O * tanh_f(cn);                                                  \
      if (s_ >= 2) { c2s = cn;                                                    \
        if (cmt) { Pn[wr_base + H2O] = (_Float16)hn;                              \
          long oi = (long)(s_ - 2) * ((long)BB * HH) + olane;                     \
          if (isbf) ((__hip_bfloat16*)outp)[oi] = __float2bfloat16(hn);           \
          else ((float*)outp)[oi] = hn; } } }                                     \
    if (loader) *(halfx8*)&Pn[(tid >> 1) * SROW + XO + (tid & 1) * 8] = xreg;     \
  }

__launch_bounds__(512, 2)
__global__ void lstm3_k(const void* __restrict__ xg,
                        const void* W0i, const void* W0h, const void* B0i, const void* B0h,
                        const void* W1i, const void* W1h, const void* B1i, const void* B1h,
                        const void* W2i, const void* W2h, const void* B2i, const void* B2h,
                        void* __restrict__ outp, const int* __restrict__ flagp) {
  const int tid = threadIdx.x;
  const int w = tid >> 6;        // wave 0..7
  const int lane = tid & 63;
  const int c = lane & 15;       // MFMA col: batch row c&3, 4x duplicated
  const int g = lane >> 4;       // k-slot group
  const int rowbase = blockIdx.x * NR;
  const int isbf = flagp ? flagp[0] : 1;

  // Panel row r (4 rows): [h0(0..63) | h1(64..127) | h2(128..191) | x(192..207)]
  // +32 zeroed tail halves for L0's g>=2 zero-weight over-reads on the last row.
  __shared__ __align__(16) _Float16 SH[2 * PANEL + 32];

  auto ldf = [&](const void* b, long i) -> float {
    return isbf ? __bfloat162float(((const __hip_bfloat16*)b)[i]) : ((const float*)b)[i];
  };
  auto ld8 = [&](const void* b, long i) -> halfx8 {
    halfx8 r;
    if (isbf) {
      ushortx8 raw = *(const ushortx8*)((const unsigned short*)b + i);
#pragma unroll
      for (int j = 0; j < 8; ++j)
        r[j] = (_Float16)__uint_as_float(((unsigned int)raw[j]) << 16);
    } else {
      const float* s = (const float*)b + i;
#pragma unroll
      for (int j = 0; j < 8; ++j) r[j] = (_Float16)s[j];
    }
    return r;
  };

  // ---- persistent weight fragments + combined biases ----
  // Interleaved gate row r_il = 4*unit + q <-> orig row q*64 + unit.
  halfx8 wA0[2][3], wA1[2][4], wA2[2][4];
  floatx4 bs0[2], bs1[2], bs2[2];
#pragma unroll
  for (int m = 0; m < 2; ++m) {
    const int Mt = 2 * w + m;
    const int ril = Mt * 16 + c;
    const int u = ril >> 2, q = ril & 3;
    const long orig = q * 64 + u;
    halfx8 z = {};
    wA0[m][0] = ld8(W0h, orig * 64 + 8 * g);
    wA0[m][1] = ld8(W0h, orig * 64 + 32 + 8 * g);
    wA0[m][2] = (g == 0) ? ld8(W0i, orig * 16)
              : (g == 1) ? ld8(W0i, orig * 16 + 8) : z;
    wA1[m][0] = ld8(W1i, orig * 64 + 8 * g);
    wA1[m][1] = ld8(W1i, orig * 64 + 32 + 8 * g);
    wA1[m][2] = ld8(W1h, orig * 64 + 8 * g);
    wA1[m][3] = ld8(W1h, orig * 64 + 32 + 8 * g);
    wA2[m][0] = ld8(W2i, orig * 64 + 8 * g);
    wA2[m][1] = ld8(W2i, orig * 64 + 32 + 8 * g);
    wA2[m][2] = ld8(W2h, orig * 64 + 8 * g);
    wA2[m][3] = ld8(W2h, orig * 64 + 32 + 8 * g);
    const int ub = 4 * Mt + g;
#pragma unroll
    for (int qq = 0; qq < 4; ++qq) {
      bs0[m][qq] = ldf(B0i, 64 * qq + ub) + ldf(B0h, 64 * qq + ub);
      bs1[m][qq] = ldf(B1i, 64 * qq + ub) + ldf(B1h, 64 * qq + ub);
      bs2[m][qq] = ldf(B2i, 64 * qq + ub) + ldf(B2h, 64 * qq + ub);
    }
  }

  for (int i = tid; i < 2 * PANEL + 32; i += 512) SH[i] = (_Float16)0.0f;
  block_sync();
  if (tid < 2 * NR) {  // stage x[0] into parity-0 panel
    *(halfx8*)&SH[(tid >> 1) * SROW + XO + (tid & 1) * 8] =
        ld8(xg, ((long)0 * BB + rowbase + (tid >> 1)) * DD + (tid & 1) * 8);
  }

  // Cells: lane (c,g) of wave w holds cell (unit 8w+4*msel+g, row c&3), msel=(c>>2)&1.
  // Lanes c>=8 are exact duplicates of c-8; only c<8 commits (cmt).
  const int msel = (c >> 2) & 1;
  const int r_el = c & 3;
  const int u_el = 8 * w + 4 * msel + g;
  const bool cmt = (c < 8);
  const int rd_off = (c & 3) * SROW + 8 * g;
  const int wr_base = r_el * SROW + u_el;
  const long olane = ((long)rowbase + r_el) * HH + u_el;
  float c0s = 0.f, c1s = 0.f, c2s = 0.f;

#pragma unroll 1
  for (int s2 = 0; s2 < (TT + 2) / 2; ++s2) {
    const int s = 2 * s2;
    BODY(s, 0, PANEL)
    BODY(s + 1, PANEL, 0)
  }
}

extern "C" void kernel_launch(void* const* d_in, const int* in_sizes, int n_in,
                              void* d_out, int out_size, void* d_ws, size_t ws_size,
                              hipStream_t stream) {
  (void)in_sizes; (void)n_in; (void)out_size;
  int* flag = (ws_size >= sizeof(int)) ? (int*)d_ws : nullptr;
  if (flag) {
    detect_k<<<dim3(1), dim3(64), 0, stream>>>((const unsigned short*)d_in[0], flag);
  }
  lstm3_k<<<dim3(BB / NR), dim3(512), 0, stream>>>(
      d_in[0],
      d_in[1], d_in[2], d_in[3], d_in[4],
      d_in[5], d_in[6], d_in[7], d_in[8],
      d_in[9], d_in[10], d_in[11], d_in[12],
      d_out, flag);
}

// Round 6
// 296.349 us; speedup vs baseline: 7.5660x; 1.7453x over previous
//
#include <hip/hip_runtime.h>
#include <hip/hip_bf16.h>

// RecurrentLSTMStack: T=256, B=2048, D=16, H=64, 3 layers.
// R6: R3 geometry (grid 256, 8 rows/block, dup x2 cols, layer-diagonal
// pipeline, 1 barrier/superstep) + paired-tile LDS reads: dup-lane pairs
// (c, c+8) read DIFFERENT K-tiles (even/odd of each h pair), exchanged via
// VALU-pipe DPP row_ror:8 -> 4 ds_read_b128/wave instead of 7. LDS read
// burst was the dominant pipe (56 instr x 12cyc/CU/superstep).

#define TT 256
#define BB 2048
#define DD 16
#define HH 64

#define SROW 216                 // halves/row; 108 words, 108%32=12 -> spread banks
#define PANEL (8 * SROW)         // 1728 halves per parity panel
#define H0O 0
#define H1O 64
#define H2O 128
#define XO  192

typedef __attribute__((ext_vector_type(8))) _Float16 halfx8;
typedef __attribute__((ext_vector_type(8))) unsigned short ushortx8;
typedef __attribute__((ext_vector_type(4))) float floatx4;

#if __has_builtin(__builtin_amdgcn_exp2f)
#define EXP2F(x) __builtin_amdgcn_exp2f(x)
#else
#define EXP2F(x) exp2f(x)
#endif
#if __has_builtin(__builtin_amdgcn_rcpf)
#define RCPF(x) __builtin_amdgcn_rcpf(x)
#else
#define RCPF(x) (1.0f/(x))
#endif

__device__ __forceinline__ float sigm(float x) {
  return RCPF(1.0f + EXP2F(-1.4426950408889634f * x));
}
// no clamp: exp2(+inf)=inf -> rcp=0 -> 1; exp2(-inf)=0 -> 1-2/1 = -1
__device__ __forceinline__ float tanh_f(float x) {
  float t = EXP2F(2.8853900817779268f * x);
  return 1.0f - 2.0f * RCPF(t + 1.0f);
}
// Raw barrier: waits our ds ops, does NOT drain vmcnt (x prefetch stays in flight).
__device__ __forceinline__ void block_sync() {
  asm volatile("s_waitcnt lgkmcnt(0)" ::: "memory");
  __builtin_amdgcn_s_barrier();
}

// VALU-pipe lane exchange c <-> c+8 within each 16-lane row (row_ror:8 = 0x128).
// NOT __shfl (that is ds_bpermute = LDS pipe, which we are offloading).
__device__ __forceinline__ halfx8 dpp_xor8(halfx8 v) {
  union { halfx8 h; int i[4]; } u, d;
  u.h = v;
#pragma unroll
  for (int k = 0; k < 4; ++k)
    d.i[k] = __builtin_amdgcn_update_dpp(0, u.i[k], 0x128, 0xf, 0xf, true);
  return d.h;
}

__global__ void detect_k(const unsigned short* __restrict__ xr, int* __restrict__ flag) {
  int cnt = 0;
  for (int i = threadIdx.x; i < 4096; i += 64) {
    float v = __uint_as_float(((unsigned int)xr[i]) << 16);
    if (!(fabsf(v) < 4.0f)) cnt++;
  }
#pragma unroll
  for (int o = 32; o > 0; o >>= 1) cnt += __shfl_down(cnt, o, 64);
  if (threadIdx.x == 0) flag[0] = (cnt < 100) ? 1 : 0;
}

#define MF(A, B, C) __builtin_amdgcn_mfma_f32_16x16x32_f16(A, B, C, 0, 0, 0)

#define BODY(S_, PPB, PNB)                                                        \
  {                                                                               \
    const int s_ = (S_);                                                          \
    halfx8 xreg = {};                                                             \
    const bool loader = (tid < 16) && (s_ + 1 < TT);                              \
    if (loader)                                                                   \
      xreg = ld8(xg, ((long)(s_ + 1) * BB + rowbase + (tid >> 1)) * DD + (tid & 1) * 8); \
    block_sync();                                                                 \
    const _Float16* PpR = SH + (PPB) + rd_off2;                                   \
    _Float16* Pn = SH + (PNB);                                                    \
    halfx8 pA = *(const halfx8*)(PpR + 0);     /* t0 (c<8) | t1 (c>=8) : h0 */    \
    halfx8 pB = *(const halfx8*)(PpR + 64);    /* t2 | t3 : h1 */                 \
    halfx8 pC = *(const halfx8*)(PpR + 128);   /* t4 | t5 : h2 */                 \
    halfx8 rX = *(const halfx8*)(SH + (PPB) + rd_off + 192);  /* t6 : x, all */   \
    halfx8 sA = dpp_xor8(pA);                                                     \
    halfx8 sB = dpp_xor8(pB);                                                     \
    halfx8 sC = dpp_xor8(pC);                                                     \
    halfx8 r0 = m8 ? sA : pA, r1 = m8 ? pA : sA;                                  \
    halfx8 r2 = m8 ? sB : pB, r3 = m8 ? pB : sB;                                  \
    halfx8 r4 = m8 ? sC : pC, r5 = m8 ? pC : sC;                                  \
    floatx4 a00 = bs0[0], a01 = bs0[1];                                           \
    floatx4 a10 = bs1[0], a11 = bs1[1];                                           \
    floatx4 a20 = bs2[0], a21 = bs2[1];                                           \
    __builtin_amdgcn_s_setprio(1);                                                \
    a00 = MF(wA0[0][0], r0, a00); a01 = MF(wA0[1][0], r0, a01);                   \
    a10 = MF(wA1[0][0], r0, a10); a11 = MF(wA1[1][0], r0, a11);                   \
    a00 = MF(wA0[0][1], r1, a00); a01 = MF(wA0[1][1], r1, a01);                   \
    a10 = MF(wA1[0][1], r1, a10); a11 = MF(wA1[1][1], r1, a11);                   \
    a20 = MF(wA2[0][0], r2, a20); a21 = MF(wA2[1][0], r2, a21);                   \
    a10 = MF(wA1[0][2], r2, a10); a11 = MF(wA1[1][2], r2, a11);                   \
    a20 = MF(wA2[0][1], r3, a20); a21 = MF(wA2[1][1], r3, a21);                   \
    a10 = MF(wA1[0][3], r3, a10); a11 = MF(wA1[1][3], r3, a11);                   \
    a20 = MF(wA2[0][2], r4, a20); a21 = MF(wA2[1][2], r4, a21);                   \
    a20 = MF(wA2[0][3], r5, a20); a21 = MF(wA2[1][3], r5, a21);                   \
    a00 = MF(wA0[0][2], rX, a00); a01 = MF(wA0[1][2], rX, a01);                   \
    __builtin_amdgcn_s_setprio(0);                                                \
    { floatx4 gv = m8 ? a01 : a00;                                                \
      float I = sigm(gv[0]), F = sigm(gv[1]), G = tanh_f(gv[2]), O = sigm(gv[3]); \
      float cn = F * c0s + I * G;                                                 \
      float hn = O * tanh_f(cn);                                                  \
      if (s_ < TT) { c0s = cn; Pn[wr_base + H0O] = (_Float16)hn; } }              \
    { floatx4 gv = m8 ? a11 : a10;                                                \
      float I = sigm(gv[0]), F = sigm(gv[1]), G = tanh_f(gv[2]), O = sigm(gv[3]); \
      float cn = F * c1s + I * G;                                                 \
      float hn = O * tanh_f(cn);                                                  \
      if (s_ >= 1 && s_ <= TT) { c1s = cn; Pn[wr_base + H1O] = (_Float16)hn; } }  \
    { floatx4 gv = m8 ? a21 : a20;                                                \
      float I = sigm(gv[0]), F = sigm(gv[1]), G = tanh_f(gv[2]), O = sigm(gv[3]); \
      float cn = F * c2s + I * G;                                                 \
      float hn = O * tanh_f(cn);                                                  \
      if (s_ >= 2) { c2s = cn; Pn[wr_base + H2O] = (_Float16)hn;                  \
        long oi = (long)(s_ - 2) * ((long)BB * HH) + olane;                       \
        if (isbf) ((__hip_bfloat16*)outp)[oi] = __float2bfloat16(hn);             \
        else ((float*)outp)[oi] = hn; } }                                         \
    if (loader) *(halfx8*)&Pn[(tid >> 1) * SROW + XO + (tid & 1) * 8] = xreg;     \
  }

__launch_bounds__(512, 2)
__global__ void lstm3_k(const void* __restrict__ xg,
                        const void* W0i, const void* W0h, const void* B0i, const void* B0h,
                        const void* W1i, const void* W1h, const void* B1i, const void* B1h,
                        const void* W2i, const void* W2h, const void* B2i, const void* B2h,
                        void* __restrict__ outp, const int* __restrict__ flagp) {
  const int tid = threadIdx.x;
  const int w = tid >> 6;        // wave 0..7
  const int lane = tid & 63;
  const int c = lane & 15;       // MFMA col (batch row, duplicated 8..15)
  const int g = lane >> 4;       // k-slot group
  const int rowbase = blockIdx.x * 8;
  const int isbf = flagp ? flagp[0] : 1;

  // Panel row r: [h0(0..63) | h1(64..127) | h2(128..191) | x(192..207) | pad]
  // +32 zeroed tail: row-7 g=3 x-tile over-read (weights there are zero).
  __shared__ __align__(16) _Float16 SH[2 * PANEL + 32];

  auto ldf = [&](const void* b, long i) -> float {
    return isbf ? __bfloat162float(((const __hip_bfloat16*)b)[i]) : ((const float*)b)[i];
  };
  auto ld8 = [&](const void* b, long i) -> halfx8 {
    halfx8 r;
    if (isbf) {
      ushortx8 raw = *(const ushortx8*)((const unsigned short*)b + i);
#pragma unroll
      for (int j = 0; j < 8; ++j)
        r[j] = (_Float16)__uint_as_float(((unsigned int)raw[j]) << 16);
    } else {
      const float* s = (const float*)b + i;
#pragma unroll
      for (int j = 0; j < 8; ++j) r[j] = (_Float16)s[j];
    }
    return r;
  };

  // ---- persistent weight fragments + combined biases ----
  // Interleaved gate row r_il = 4*unit + q <-> orig row q*64 + unit.
  halfx8 wA0[2][3], wA1[2][4], wA2[2][4];
  floatx4 bs0[2], bs1[2], bs2[2];
#pragma unroll
  for (int m = 0; m < 2; ++m) {
    const int Mt = 2 * w + m;
    const int ril = Mt * 16 + c;
    const int u = ril >> 2, q = ril & 3;
    const long orig = q * 64 + u;
    halfx8 z = {};
    wA0[m][0] = ld8(W0h, orig * 64 + 8 * g);
    wA0[m][1] = ld8(W0h, orig * 64 + 32 + 8 * g);
    wA0[m][2] = (g == 0) ? ld8(W0i, orig * 16)
              : (g == 1) ? ld8(W0i, orig * 16 + 8) : z;
    wA1[m][0] = ld8(W1i, orig * 64 + 8 * g);
    wA1[m][1] = ld8(W1i, orig * 64 + 32 + 8 * g);
    wA1[m][2] = ld8(W1h, orig * 64 + 8 * g);
    wA1[m][3] = ld8(W1h, orig * 64 + 32 + 8 * g);
    wA2[m][0] = ld8(W2i, orig * 64 + 8 * g);
    wA2[m][1] = ld8(W2i, orig * 64 + 32 + 8 * g);
    wA2[m][2] = ld8(W2h, orig * 64 + 8 * g);
    wA2[m][3] = ld8(W2h, orig * 64 + 32 + 8 * g);
    const int ub = 4 * Mt + g;
#pragma unroll
    for (int qq = 0; qq < 4; ++qq) {
      bs0[m][qq] = ldf(B0i, 64 * qq + ub) + ldf(B0h, 64 * qq + ub);
      bs1[m][qq] = ldf(B1i, 64 * qq + ub) + ldf(B1h, 64 * qq + ub);
      bs2[m][qq] = ldf(B2i, 64 * qq + ub) + ldf(B2h, 64 * qq + ub);
    }
  }

  for (int i = tid; i < 2 * PANEL + 32; i += 512) SH[i] = (_Float16)0.0f;
  block_sync();
  if (tid < 16) {  // stage x[0] into parity-0 panel
    *(halfx8*)&SH[(tid >> 1) * SROW + XO + (tid & 1) * 8] =
        ld8(xg, ((long)0 * BB + rowbase + (tid >> 1)) * DD + (tid & 1) * 8);
  }

  // Cells: lane (c,g) of wave w owns (unit 8w + 4*m8 + g, row c&7) -> all 64
  // lanes distinct cells (elementwise-optimal). m8 = c>=8 also selects the
  // odd K-tile for the paired read.
  const bool m8 = (c >= 8);
  const int r_el = c & 7;
  const int u_el = 8 * w + (m8 ? 4 + g : g);
  const int rd_off = r_el * SROW + 8 * g;
  const int rd_off2 = rd_off + (m8 ? 32 : 0);
  const int wr_base = r_el * SROW + u_el;
  const long olane = ((long)rowbase + r_el) * HH + u_el;
  float c0s = 0.f, c1s = 0.f, c2s = 0.f;

#pragma unroll 1
  for (int s2 = 0; s2 < (TT + 2) / 2; ++s2) {
    const int s = 2 * s2;
    BODY(s, 0, PANEL)
    BODY(s + 1, PANEL, 0)
  }
}

extern "C" void kernel_launch(void* const* d_in, const int* in_sizes, int n_in,
                              void* d_out, int out_size, void* d_ws, size_t ws_size,
                              hipStream_t stream) {
  (void)in_sizes; (void)n_in; (void)out_size;
  int* flag = (ws_size >= sizeof(int)) ? (int*)d_ws : nullptr;
  if (flag) {
    detect_k<<<dim3(1), dim3(64), 0, stream>>>((const unsigned short*)d_in[0], flag);
  }
  lstm3_k<<<dim3(BB / 8), dim3(512), 0, stream>>>(
      d_in[0],
      d_in[1], d_in[2], d_in[3], d_in[4],
      d_in[5], d_in[6], d_in[7], d_in[8],
      d_in[9], d_in[10], d_in[11], d_in[12],
      d_out, flag);
}